// Round 1
// baseline (1099.970 us; speedup 1.0000x reference)
//
#include <hip/hip_runtime.h>
#include <cstdint>

#define NTOK 8192
#define CDIM 1024
#define HDIM 1408
#define HSDIM 2816
#define NEXP 8

typedef __attribute__((ext_vector_type(8))) short s8v;
typedef __attribute__((ext_vector_type(4))) float f4v;

__device__ __forceinline__ unsigned short f2bf(float f) {
    unsigned int u = __float_as_uint(f);
    unsigned int r = (u + 0x7fffu + ((u >> 16) & 1u)) >> 16;  // RNE
    return (unsigned short)r;
}

__device__ __forceinline__ void g2l16(unsigned short* lds, const unsigned short* g) {
    __builtin_amdgcn_global_load_lds(
        (const __attribute__((address_space(1))) unsigned int*)g,
        (__attribute__((address_space(3))) unsigned int*)lds, 16, 0, 0);
}

// ---------------- conversion kernels ----------------

__global__ void cvt_bf16_kernel(const float4* __restrict__ in, ushort4* __restrict__ out, int n4) {
    int i = blockIdx.x * blockDim.x + threadIdx.x;
    if (i < n4) {
        float4 v = in[i];
        ushort4 o;
        o.x = f2bf(v.x); o.y = f2bf(v.y); o.z = f2bf(v.z); o.w = f2bf(v.w);
        out[i] = o;
    }
}

// in: fp32 [batch][R][Cc] -> out: bf16 [batch][Cc][R]
__global__ void transpose_cvt_kernel(const float* __restrict__ in, unsigned short* __restrict__ out,
                                     int R, int Cc) {
    __shared__ unsigned short tile[32][33];
    const size_t bstride = (size_t)R * Cc;
    const float* bin = in + blockIdx.z * bstride;
    unsigned short* bout = out + blockIdx.z * bstride;
    int c0 = blockIdx.x * 32, r0 = blockIdx.y * 32;
    int x = threadIdx.x, y = threadIdx.y;  // 32 x 8
#pragma unroll
    for (int i = 0; i < 4; i++) {
        int r = r0 + y + i * 8;
        tile[y + i * 8][x] = f2bf(bin[(size_t)r * Cc + c0 + x]);
    }
    __syncthreads();
#pragma unroll
    for (int i = 0; i < 4; i++) {
        int cc = y + i * 8;
        bout[(size_t)(c0 + cc) * R + r0 + x] = tile[x][cc];
    }
}

// ---------------- router ----------------
// one wave per token; fp32 dots so top-k selection matches reference exactly
__global__ void router_kernel(const float* __restrict__ x, const float* __restrict__ Wg,
                              int* __restrict__ idxK, float* __restrict__ probK,
                              int* __restrict__ meta) {
    int t = blockIdx.x;
    int lane = threadIdx.x;
    const float* xr = x + (size_t)t * CDIM;
    float acc[NEXP];
#pragma unroll
    for (int e = 0; e < NEXP; e++) acc[e] = 0.f;
    for (int c = lane; c < CDIM; c += 64) {
        float xv = xr[c];
        const float* wr = Wg + c * NEXP;
#pragma unroll
        for (int e = 0; e < NEXP; e++) acc[e] += xv * wr[e];
    }
#pragma unroll
    for (int e = 0; e < NEXP; e++)
        for (int off = 32; off > 0; off >>= 1)
            acc[e] += __shfl_down(acc[e], off, 64);
    if (lane == 0) {
        int b0 = 0; float v0 = acc[0];
#pragma unroll
        for (int e = 1; e < NEXP; e++) if (acc[e] > v0) { v0 = acc[e]; b0 = e; }
        int b1 = -1; float v1 = -1e30f;
#pragma unroll
        for (int e = 0; e < NEXP; e++) if (e != b0 && acc[e] > v1) { v1 = acc[e]; b1 = e; }
        float p0 = 1.f / (1.f + __expf(v1 - v0));  // softmax over [v0, v1]
        idxK[2 * t] = b0; idxK[2 * t + 1] = b1;
        probK[2 * t] = p0; probK[2 * t + 1] = 1.f - p0;
        atomicAdd(&meta[b0], 1);
        atomicAdd(&meta[b1], 1);
    }
}

// meta: [0..7] counts, [8..15] offsets, [16..23] cursor
__global__ void offsets_kernel(int* meta) {
    int s = 0;
    for (int e = 0; e < NEXP; e++) { meta[8 + e] = s; meta[16 + e] = s; s += meta[e]; }
}

__global__ void fill_kernel(const int* __restrict__ idxK, const float* __restrict__ probK,
                            int* __restrict__ meta, int* __restrict__ rowT, float* __restrict__ rowW) {
    int t = blockIdx.x * 256 + threadIdx.x;
    if (t >= NTOK) return;
#pragma unroll
    for (int k = 0; k < 2; k++) {
        int e = idxK[2 * t + k];
        int p = atomicAdd(&meta[16 + e], 1);
        rowT[p] = t;
        rowW[p] = probK[2 * t + k];
    }
}

// ---------------- fused gate GEMM: H = silu(A@W1) * (A@W2) ----------------
// BM=128, BN=64, BK=32. 256 threads = 4 waves in 2x2. bf16 in/out, fp32 acc.
template <bool GATHER>
__global__ __launch_bounds__(256) void gemm12_kernel(
    const unsigned short* __restrict__ A, const unsigned short* __restrict__ B1g,
    const unsigned short* __restrict__ B2g, unsigned short* __restrict__ Hout,
    int N, int K, int Mdir, const int* __restrict__ rowT, const int* __restrict__ meta) {
    const int e = GATHER ? blockIdx.z : 0;
    const int M = GATHER ? meta[e] : Mdir;
    const int base = GATHER ? meta[8 + e] : 0;
    const int m0 = blockIdx.x * 128;
    if (m0 >= M) return;
    const int n0 = blockIdx.y * 64;

    __shared__ unsigned short As[128 * 32];
    __shared__ unsigned short Bs1[64 * 32];
    __shared__ unsigned short Bs2[64 * 32];

    const int tid = threadIdx.x;
    const int r4 = tid >> 2, c4 = tid & 3;

    int am0 = m0 + r4;        am0 = am0 < M ? am0 : M - 1;
    int am1 = m0 + 64 + r4;   am1 = am1 < M ? am1 : M - 1;
    long ar0, ar1;
    if (GATHER) { ar0 = rowT[base + am0]; ar1 = rowT[base + am1]; }
    else        { ar0 = am0;              ar1 = am1; }

    const unsigned short* a0p = A + (size_t)ar0 * K + c4 * 8;
    const unsigned short* a1p = A + (size_t)ar1 * K + c4 * 8;
    const unsigned short* b1p = B1g + (size_t)e * N * K + (size_t)(n0 + r4) * K + c4 * 8;
    const unsigned short* b2p = B2g + (size_t)e * N * K + (size_t)(n0 + r4) * K + c4 * 8;
    unsigned short* lA0 = As + tid * 8;
    unsigned short* lA1 = As + 2048 + tid * 8;
    unsigned short* lB1 = Bs1 + tid * 8;
    unsigned short* lB2 = Bs2 + tid * 8;

    const int w = tid >> 6, lane = tid & 63;
    const int wm = (w >> 1) * 64, wn = (w & 1) * 32;
    const int quad = lane >> 4, l15 = lane & 15;

    f4v acc1[4][2], acc2[4][2];
#pragma unroll
    for (int i = 0; i < 4; i++)
#pragma unroll
        for (int j = 0; j < 2; j++) {
            f4v z = {0.f, 0.f, 0.f, 0.f};
            acc1[i][j] = z; acc2[i][j] = z;
        }

    for (int k0 = 0; k0 < K; k0 += 32) {
        g2l16(lA0, a0p + k0);
        g2l16(lA1, a1p + k0);
        g2l16(lB1, b1p + k0);
        g2l16(lB2, b2p + k0);
        __syncthreads();
        s8v af[4], bf1[2], bf2[2];
#pragma unroll
        for (int mt = 0; mt < 4; mt++)
            af[mt] = *(const s8v*)(As + (wm + mt * 16 + l15) * 32 + quad * 8);
#pragma unroll
        for (int nt = 0; nt < 2; nt++) {
            bf1[nt] = *(const s8v*)(Bs1 + (wn + nt * 16 + l15) * 32 + quad * 8);
            bf2[nt] = *(const s8v*)(Bs2 + (wn + nt * 16 + l15) * 32 + quad * 8);
        }
#pragma unroll
        for (int mt = 0; mt < 4; mt++)
#pragma unroll
            for (int nt = 0; nt < 2; nt++) {
                acc1[mt][nt] = __builtin_amdgcn_mfma_f32_16x16x32_bf16(af[mt], bf1[nt], acc1[mt][nt], 0, 0, 0);
                acc2[mt][nt] = __builtin_amdgcn_mfma_f32_16x16x32_bf16(af[mt], bf2[nt], acc2[mt][nt], 0, 0, 0);
            }
        __syncthreads();
    }

#pragma unroll
    for (int mt = 0; mt < 4; mt++) {
#pragma unroll
        for (int r = 0; r < 4; r++) {
            int gm = m0 + wm + mt * 16 + quad * 4 + r;
            if (gm < M) {
                size_t rowoff = (size_t)(base + gm) * N;
#pragma unroll
                for (int nt = 0; nt < 2; nt++) {
                    float z1 = acc1[mt][nt][r];
                    float z2 = acc2[mt][nt][r];
                    float hv = (z1 / (1.f + __expf(-z1))) * z2;
                    Hout[rowoff + n0 + wn + nt * 16 + l15] = f2bf(hv);
                }
            }
        }
    }
}

// ---------------- down-proj GEMM: Out = H @ W3 (N fixed = 1024) ----------------
// BM=128, BN=128, BK=32. SCATTER: atomicAdd weighted into token rows.
template <bool SCATTER>
__global__ __launch_bounds__(256) void gemm3_kernel(
    const unsigned short* __restrict__ A, const unsigned short* __restrict__ Bg,
    float* __restrict__ Out, int K, int Mdir,
    const int* __restrict__ rowT, const float* __restrict__ rowW, const int* __restrict__ meta) {
    const int e = SCATTER ? blockIdx.z : 0;
    const int M = SCATTER ? meta[e] : Mdir;
    const int base = SCATTER ? meta[8 + e] : 0;
    const int m0 = blockIdx.x * 128;
    if (m0 >= M) return;
    const int n0 = blockIdx.y * 128;

    __shared__ unsigned short As[128 * 32];
    __shared__ unsigned short Bs[128 * 32];

    const int tid = threadIdx.x;
    const int r4 = tid >> 2, c4 = tid & 3;
    int am0 = m0 + r4;       am0 = am0 < M ? am0 : M - 1;
    int am1 = m0 + 64 + r4;  am1 = am1 < M ? am1 : M - 1;
    const unsigned short* a0p = A + (size_t)(base + am0) * K + c4 * 8;
    const unsigned short* a1p = A + (size_t)(base + am1) * K + c4 * 8;
    const unsigned short* b0p = Bg + (size_t)e * 1024 * K + (size_t)(n0 + r4) * K + c4 * 8;
    const unsigned short* b1p = b0p + (size_t)64 * K;
    unsigned short* lA0 = As + tid * 8;
    unsigned short* lA1 = As + 2048 + tid * 8;
    unsigned short* lB0 = Bs + tid * 8;
    unsigned short* lB1 = Bs + 2048 + tid * 8;

    const int w = tid >> 6, lane = tid & 63;
    const int wm = (w >> 1) * 64, wn = (w & 1) * 64;
    const int quad = lane >> 4, l15 = lane & 15;

    f4v acc[4][4];
#pragma unroll
    for (int i = 0; i < 4; i++)
#pragma unroll
        for (int j = 0; j < 4; j++) {
            f4v z = {0.f, 0.f, 0.f, 0.f};
            acc[i][j] = z;
        }

    for (int k0 = 0; k0 < K; k0 += 32) {
        g2l16(lA0, a0p + k0);
        g2l16(lA1, a1p + k0);
        g2l16(lB0, b0p + k0);
        g2l16(lB1, b1p + k0);
        __syncthreads();
        s8v af[4], bf[4];
#pragma unroll
        for (int mt = 0; mt < 4; mt++)
            af[mt] = *(const s8v*)(As + (wm + mt * 16 + l15) * 32 + quad * 8);
#pragma unroll
        for (int nt = 0; nt < 4; nt++)
            bf[nt] = *(const s8v*)(Bs + (wn + nt * 16 + l15) * 32 + quad * 8);
#pragma unroll
        for (int mt = 0; mt < 4; mt++)
#pragma unroll
            for (int nt = 0; nt < 4; nt++)
                acc[mt][nt] = __builtin_amdgcn_mfma_f32_16x16x32_bf16(af[mt], bf[nt], acc[mt][nt], 0, 0, 0);
        __syncthreads();
    }

#pragma unroll
    for (int mt = 0; mt < 4; mt++) {
#pragma unroll
        for (int r = 0; r < 4; r++) {
            int gm = m0 + wm + mt * 16 + quad * 4 + r;
            if (gm < M) {
                if (SCATTER) {
                    int rr = base + gm;
                    int t = rowT[rr];
                    float wgt = rowW[rr];
                    size_t o = (size_t)t * 1024 + n0 + wn + l15;
#pragma unroll
                    for (int nt = 0; nt < 4; nt++)
                        atomicAdd(&Out[o + nt * 16], wgt * acc[mt][nt][r]);
                } else {
                    size_t o = (size_t)gm * 1024 + n0 + wn + l15;
#pragma unroll
                    for (int nt = 0; nt < 4; nt++)
                        Out[o + nt * 16] = acc[mt][nt][r];
                }
            }
        }
    }
}

// ---------------- launch ----------------

extern "C" void kernel_launch(void* const* d_in, const int* in_sizes, int n_in,
                              void* d_out, int out_size, void* d_ws, size_t ws_size,
                              hipStream_t stream) {
    const float* x   = (const float*)d_in[0];
    const float* Wg  = (const float*)d_in[1];
    const float* W1  = (const float*)d_in[2];
    const float* W2  = (const float*)d_in[3];
    const float* W3  = (const float*)d_in[4];
    const float* Ws1 = (const float*)d_in[5];
    const float* Ws2 = (const float*)d_in[6];
    const float* Ws3 = (const float*)d_in[7];
    float* out = (float*)d_out;

    // workspace carve (~150 MB total)
    char* p = (char*)d_ws;
    auto carve = [&](size_t bytes) {
        char* r = p;
        p += (bytes + 255) & ~(size_t)255;
        return r;
    };
    unsigned short* xb   = (unsigned short*)carve((size_t)NTOK * CDIM * 2);
    unsigned short* w1t  = (unsigned short*)carve((size_t)NEXP * HDIM * CDIM * 2);
    unsigned short* w2t  = (unsigned short*)carve((size_t)NEXP * HDIM * CDIM * 2);
    unsigned short* w3t  = (unsigned short*)carve((size_t)NEXP * CDIM * HDIM * 2);
    unsigned short* ws1t = (unsigned short*)carve((size_t)HSDIM * CDIM * 2);
    unsigned short* ws2t = (unsigned short*)carve((size_t)HSDIM * CDIM * 2);
    unsigned short* ws3t = (unsigned short*)carve((size_t)CDIM * HSDIM * 2);
    unsigned short* hbuf = (unsigned short*)carve((size_t)2 * NTOK * HDIM * 2);  // shared hs & expert h (sequential reuse)
    int*   idxK  = (int*)carve((size_t)NTOK * 2 * 4);
    float* probK = (float*)carve((size_t)NTOK * 2 * 4);
    int*   rowT  = (int*)carve((size_t)2 * NTOK * 4);
    float* rowW  = (float*)carve((size_t)2 * NTOK * 4);
    int*   meta  = (int*)carve(256);

    dim3 tb(32, 8);
    // conversions / transposes (weights -> bf16 [n][k] layout)
    cvt_bf16_kernel<<<(NTOK * CDIM / 4 + 255) / 256, 256, 0, stream>>>((const float4*)x, (ushort4*)xb, NTOK * CDIM / 4);
    transpose_cvt_kernel<<<dim3(HDIM / 32, CDIM / 32, NEXP), tb, 0, stream>>>(W1, w1t, CDIM, HDIM);
    transpose_cvt_kernel<<<dim3(HDIM / 32, CDIM / 32, NEXP), tb, 0, stream>>>(W2, w2t, CDIM, HDIM);
    transpose_cvt_kernel<<<dim3(CDIM / 32, HDIM / 32, NEXP), tb, 0, stream>>>(W3, w3t, HDIM, CDIM);
    transpose_cvt_kernel<<<dim3(HSDIM / 32, CDIM / 32, 1), tb, 0, stream>>>(Ws1, ws1t, CDIM, HSDIM);
    transpose_cvt_kernel<<<dim3(HSDIM / 32, CDIM / 32, 1), tb, 0, stream>>>(Ws2, ws2t, CDIM, HSDIM);
    transpose_cvt_kernel<<<dim3(CDIM / 32, HSDIM / 32, 1), tb, 0, stream>>>(Ws3, ws3t, HSDIM, CDIM);

    // routing
    hipMemsetAsync(meta, 0, 256, stream);
    router_kernel<<<NTOK, 64, 0, stream>>>(x, Wg, idxK, probK, meta);
    offsets_kernel<<<1, 1, 0, stream>>>(meta);
    fill_kernel<<<NTOK / 256, 256, 0, stream>>>(idxK, probK, meta, rowT, rowW);

    // shared expert path (writes out plainly -> initializes every element)
    gemm12_kernel<false><<<dim3(NTOK / 128, HSDIM / 64), 256, 0, stream>>>(
        xb, ws1t, ws2t, hbuf, HSDIM, CDIM, NTOK, nullptr, nullptr);
    gemm3_kernel<false><<<dim3(NTOK / 128, CDIM / 128), 256, 0, stream>>>(
        hbuf, ws3t, out, HSDIM, NTOK, nullptr, nullptr, nullptr);

    // routed expert path (atomic-adds on top; hbuf reused, stream-ordered)
    gemm12_kernel<true><<<dim3(NTOK / 128, HDIM / 64, NEXP), 256, 0, stream>>>(
        xb, w1t, w2t, hbuf, HDIM, CDIM, 0, rowT, meta);
    gemm3_kernel<true><<<dim3(NTOK / 128, CDIM / 128, NEXP), 256, 0, stream>>>(
        hbuf, w3t, out, HDIM, 0, rowT, rowW, meta);
}